// Round 8
// baseline (223.391 us; speedup 1.0000x reference)
//
#include <hip/hip_runtime.h>
#include <hip/hip_bf16.h>

#define B_ 8
#define N_ 2048
#define FIN_ 128
#define FO_ 64
#define ALPHA_ 0.2f
#define NEGINF_ -1000000000.0f

typedef __attribute__((ext_vector_type(8))) short short8;
typedef __attribute__((ext_vector_type(4))) float f32x4;

// round-to-nearest-even f32 -> bf16 bits, and back
__device__ __forceinline__ unsigned bf16_rne(float x) {
    union { float f; unsigned u; } v; v.f = x;
    return (v.u + 0x7FFFu + ((v.u >> 16) & 1u)) >> 16;
}
__device__ __forceinline__ float bf16_f32(unsigned b) {
    union { unsigned u; float f; } v; v.u = b << 16; return v.f;
}
// split two f32 into packed bf16 hi-word and lo-(residual)-word
__device__ __forceinline__ void split2(float x0, float x1, unsigned& hw, unsigned& lw) {
    unsigned h0 = bf16_rne(x0), h1 = bf16_rne(x1);
    unsigned l0 = bf16_rne(x0 - bf16_f32(h0));
    unsigned l1 = bf16_rne(x1 - bf16_f32(h1));
    hw = h0 | (h1 << 16);
    lw = l0 | (l1 << 16);
}

// ---------------------------------------------------------------------------
// K0: adj (int32 NxN) -> packed bitmask (uint32 N x 64). Read once: 16.8 MB.
// ---------------------------------------------------------------------------
__global__ __launch_bounds__(256) void k0_bits(
    const int* __restrict__ adj, unsigned* __restrict__ bits)
{
    int i = blockIdx.x, tid = threadIdx.x, lane = tid & 63;
#pragma unroll
    for (int c = 0; c < 8; ++c) {
        int j = c * 256 + tid;
        unsigned long long m = __ballot(adj[(size_t)i * N_ + j] > 0);
        if (lane == 0) {
            bits[(size_t)i * 64 + (j >> 5)]     = (unsigned)m;
            bits[(size_t)i * 64 + (j >> 5) + 1] = (unsigned)(m >> 32);
        }
    }
}

// ---------------------------------------------------------------------------
// K1: h_prime = h @ W; epilogue writes hpT as bf16 hi/lo TRANSPOSED [b][o][k]
// (via LDS transpose) for the fused kernel's B-frags, plus e_l/e_r.
// ---------------------------------------------------------------------------
__global__ __launch_bounds__(256) void k1_hprime(
    const float* __restrict__ h, const float* __restrict__ W,
    const float* __restrict__ a,
    unsigned short* __restrict__ hpTh, unsigned short* __restrict__ hpTl,
    float* __restrict__ el, float* __restrict__ er)
{
    __shared__ float Wl[FIN_ * FO_];
    __shared__ float al[FO_], ar[FO_];
    __shared__ float hrow[4][4][FIN_];
    __shared__ float tr[FO_][17];          // [o][k_local], padded

    int tid = threadIdx.x;
    const float4* W4 = (const float4*)W;
    float4* Wl4 = (float4*)Wl;
#pragma unroll
    for (int i = 0; i < 8; ++i) Wl4[tid + 256 * i] = W4[tid + 256 * i];
    if (tid < FO_) { al[tid] = a[tid]; ar[tid] = a[FO_ + tid]; }

    int wave = tid >> 6, lane = tid & 63;
    int row0 = blockIdx.x * 16 + wave * 4;
#pragma unroll
    for (int rr = 0; rr < 4; ++rr) {
        hrow[wave][rr][lane]      = h[(size_t)(row0 + rr) * FIN_ + lane];
        hrow[wave][rr][lane + 64] = h[(size_t)(row0 + rr) * FIN_ + lane + 64];
    }
    __syncthreads();

    float acc0 = 0.f, acc1 = 0.f, acc2 = 0.f, acc3 = 0.f;
#pragma unroll 8
    for (int k = 0; k < FIN_; ++k) {
        float w = Wl[k * FO_ + lane];
        acc0 = fmaf(hrow[wave][0][k], w, acc0);
        acc1 = fmaf(hrow[wave][1][k], w, acc1);
        acc2 = fmaf(hrow[wave][2][k], w, acc2);
        acc3 = fmaf(hrow[wave][3][k], w, acc3);
    }

    float accs[4] = {acc0, acc1, acc2, acc3};
#pragma unroll
    for (int rr = 0; rr < 4; ++rr) {
        int row = row0 + rr;
        tr[lane][wave * 4 + rr] = accs[rr];
        float pl = accs[rr] * al[lane];
        float pr = accs[rr] * ar[lane];
#pragma unroll
        for (int off = 32; off; off >>= 1) {
            pl += __shfl_xor(pl, off);
            pr += __shfl_xor(pr, off);
        }
        if (lane == 0) { el[row] = pl; er[row] = pr; }
    }
    __syncthreads();

    // transpose-out: thread t -> (o = t>>2, kq = t&3), 4 k each, bf16 hi/lo
    int o = tid >> 2, kq = tid & 3;
    int gk0 = (blockIdx.x * 16) & (N_ - 1);
    int bb  = (blockIdx.x * 16) >> 11;
    float x0 = tr[o][kq * 4 + 0], x1 = tr[o][kq * 4 + 1];
    float x2 = tr[o][kq * 4 + 2], x3 = tr[o][kq * 4 + 3];
    unsigned hw0, lw0, hw1, lw1;
    split2(x0, x1, hw0, lw0);
    split2(x2, x3, hw1, lw1);
    size_t base = ((size_t)bb * FO_ + o) * N_ + gk0 + kq * 4;
    uint2 H = {hw0, hw1}, L = {lw0, lw1};
    *(uint2*)&hpTh[base] = H;
    *(uint2*)&hpTl[base] = L;
}

// ---------------------------------------------------------------------------
// K23: fused masked-softmax + attention store + PV MFMA, LANE-LOCAL P.
// Block = (1 batch, 16 rows). Phase A: row sums. Phase B: wave w owns k in
// [w*512,(w+1)*512); lane (l15,lg) computes exactly its MFMA A-fragment
// P[l15][ks+lg*8+q], q=0..7 -> registers (no LDS transpose, no packing),
// stores attn (2 float4), 3-term hi/lo MFMA vs hpT. Cross-wave reduce.
// Batch = blockIdx.x so each XCD keeps one batch's 512KB hpT slice L2-hot.
// ---------------------------------------------------------------------------
__global__ __launch_bounds__(256, 4) void k23_fused(
    const unsigned* __restrict__ bits, const float* __restrict__ el,
    const float* __restrict__ er,
    const unsigned short* __restrict__ hpTh, const unsigned short* __restrict__ hpTl,
    float* __restrict__ attn, float* __restrict__ hout)
{
    __shared__ alignas(16) float erb[N_];            // 8 KB
    __shared__ unsigned adjw[16 * 65];               // padded rows, 4.2 KB
    __shared__ float el16[16], inv16[16];
    __shared__ float red[4][16][FO_];                // 16 KB

    int tid = threadIdx.x;
    int wave = tid >> 6, lane = tid & 63;
    int b  = blockIdx.x;
    int i0 = blockIdx.y * 16;

    // stage er row for batch b (8 KB) and 16 rows of mask words (4 KB)
    const float4* erg = (const float4*)(er + (size_t)b * N_);
    float4* erb4 = (float4*)erb;
    erb4[tid]       = erg[tid];
    erb4[tid + 256] = erg[tid + 256];
#pragma unroll
    for (int q = 0; q < 4; ++q) {
        int idx = q * 256 + tid;                      // 0..1023
        adjw[(idx >> 6) * 65 + (idx & 63)] =
            bits[(size_t)(i0 + (idx >> 6)) * 64 + (idx & 63)];
    }
    if (tid < 16) el16[tid] = el[(size_t)b * N_ + i0 + tid];
    __syncthreads();

    const float LOG2E = 1.44269504088896340736f;

    // ---- Phase A: per-row sum of exp(leaky(el+er)) over masked j ----------
    float4 ercache[8];
#pragma unroll
    for (int c = 0; c < 8; ++c) ercache[c] = erb4[c * 64 + lane];

#pragma unroll
    for (int rr = 0; rr < 4; ++rr) {
        int r = wave * 4 + rr;
        float elv = el16[r];
        float sum = 0.f;
#pragma unroll
        for (int c = 0; c < 8; ++c) {
            unsigned w = adjw[r * 65 + c * 8 + (lane >> 3)];
            int b0 = (lane & 7) * 4;
            float xs[4] = {ercache[c].x, ercache[c].y, ercache[c].z, ercache[c].w};
#pragma unroll
            for (int q = 0; q < 4; ++q) {
                float x = elv + xs[q];
                x = fmaxf(x, ALPHA_ * x);
                x = ((w >> (b0 + q)) & 1u) ? x : NEGINF_;
                sum += __builtin_amdgcn_exp2f(x * LOG2E);
            }
        }
#pragma unroll
        for (int off = 32; off; off >>= 1) sum += __shfl_xor(sum, off);
        if (lane == 0) inv16[r] = 1.0f / sum;
    }
    __syncthreads();

    // ---- Phase B: lane-local P + attn store + PV --------------------------
    int l15 = lane & 15, lg = lane >> 4;
    float pel  = el16[l15];
    float pinv = inv16[l15];
    int kbase = wave * (N_ / 4);                 // 512 k per wave
    unsigned mrow = l15 * 65;

    // arow points at this lane's j=lg*8 column of its row
    float* arow = attn + (size_t)b * N_ * N_ + (size_t)(i0 + l15) * N_ + lg * 8;
    const unsigned short* Bh = hpTh + (size_t)b * FO_ * N_;
    const unsigned short* Bl = hpTl + (size_t)b * FO_ * N_;

    f32x4 acc[4];
#pragma unroll
    for (int c = 0; c < 4; ++c) acc[c] = (f32x4){0.f, 0.f, 0.f, 0.f};

#pragma unroll 1
    for (int ks = kbase; ks < kbase + N_ / 4; ks += 32) {
        // B-fragments (L2-resident hpT)
        short8 bhi[4], blo[4];
#pragma unroll
        for (int c = 0; c < 4; ++c) {
            size_t boff = (size_t)(c * 16 + l15) * N_ + ks + lg * 8;
            bhi[c] = *(const short8*)&Bh[boff];
            blo[c] = *(const short8*)&Bl[boff];
        }

        // 8 P values this lane owns: j = ks + lg*8 + q, q=0..7
        int j0 = ks + lg * 8;
        float4 e0 = erb4[(j0 >> 2)];
        float4 e1 = erb4[(j0 >> 2) + 1];
        unsigned mw = adjw[mrow + (ks >> 5)];
        int bq = lg * 8;
        float ea[8] = {e0.x, e0.y, e0.z, e0.w, e1.x, e1.y, e1.z, e1.w};
        float p[8];
#pragma unroll
        for (int q = 0; q < 8; ++q) {
            float x = pel + ea[q];
            x = fmaxf(x, ALPHA_ * x);
            x = ((mw >> (bq + q)) & 1u) ? x : NEGINF_;
            p[q] = __builtin_amdgcn_exp2f(x * LOG2E) * pinv;
        }

        // attention store: global col j0 = arow + ks
        float4 s0 = {p[0], p[1], p[2], p[3]};
        float4 s1 = {p[4], p[5], p[6], p[7]};
        *(float4*)&arow[ks]     = s0;
        *(float4*)&arow[ks + 4] = s1;

        // A-fragments directly in registers (lane-local)
        short8 ahi, alo;
#pragma unroll
        for (int q = 0; q < 8; ++q) {
            unsigned hb = bf16_rne(p[q]);
            ahi[q] = (short)hb;
            alo[q] = (short)bf16_rne(p[q] - bf16_f32(hb));
        }

#pragma unroll
        for (int c = 0; c < 4; ++c) {
            acc[c] = __builtin_amdgcn_mfma_f32_16x16x32_bf16(ahi, bhi[c], acc[c], 0, 0, 0);
            acc[c] = __builtin_amdgcn_mfma_f32_16x16x32_bf16(ahi, blo[c], acc[c], 0, 0, 0);
            acc[c] = __builtin_amdgcn_mfma_f32_16x16x32_bf16(alo, bhi[c], acc[c], 0, 0, 0);
        }
    }

    // cross-wave reduction of 16x64 tiles
#pragma unroll
    for (int c = 0; c < 4; ++c)
#pragma unroll
        for (int r = 0; r < 4; ++r)
            red[wave][lg * 4 + r][c * 16 + l15] = acc[c][r];
    __syncthreads();

    int oo = tid & 63;
    int ib = tid >> 6;
#pragma unroll
    for (int q = 0; q < 4; ++q) {
        int i = ib * 4 + q;
        float s = (red[0][i][oo] + red[1][i][oo]) + (red[2][i][oo] + red[3][i][oo]);
        hout[((size_t)b * N_ + i0 + i) * FO_ + oo] = s;
    }
}

// ---------------------------------------------------------------------------
extern "C" void kernel_launch(void* const* d_in, const int* in_sizes, int n_in,
                              void* d_out, int out_size, void* d_ws, size_t ws_size,
                              hipStream_t stream) {
    const float* h   = (const float*)d_in[0];
    const int*   adj = (const int*)d_in[1];
    const float* W   = (const float*)d_in[2];
    const float* a   = (const float*)d_in[3];

    float* hout = (float*)d_out;                              // 8*2048*64
    float* attn = (float*)d_out + (size_t)B_ * N_ * FO_;      // 8*2048*2048

    const size_t hpN = (size_t)B_ * FO_ * N_;                 // 1,048,576
    unsigned short* hpTh = (unsigned short*)d_ws;
    unsigned short* hpTl = hpTh + hpN;
    float* elw = (float*)(hpTl + hpN);
    float* erw = elw + (size_t)B_ * N_;
    unsigned* bits = (unsigned*)(erw + (size_t)B_ * N_);      // 2048*64 u32

    k0_bits<<<N_, 256, 0, stream>>>(adj, bits);
    k1_hprime<<<(B_ * N_) / 16, 256, 0, stream>>>(h, W, a, hpTh, hpTl, elw, erw);
    k23_fused<<<dim3(B_, N_ / 16), 256, 0, stream>>>(bits, elw, erw, hpTh, hpTl, attn, hout);
}